// Round 5
// baseline (184.090 us; speedup 1.0000x reference)
//
#include <hip/hip_runtime.h>
#include <hip/hip_bf16.h>
#include <hip/hip_fp16.h>
#include <math.h>

// InnerProductDecoder: out[e] = sigmoid(dot(z1[src[e]], z2[dst[e]])), D=128.
//
// Model (R0-R3 measured): the random gather runs at a hard ~3.3 TB/s
// fetch-path plateau independent of request size and MLP. Gather bytes are
// at the fp16 floor (fp8/int8 fail the 2e-2 threshold; edge-sort locality
// is a net wash vs scatter-write cost). Remaining headroom is the convert
// pass: ~34 us vs 24.4 us stream floor (153.6 MB @ 6.29 TB/s).
//
// R4: convert v2 -- 64 B loads/thread (4x float4 nt loads), 2x float4 nt
// stores, half the threads. Gather kernel unchanged from R2/R3.

#define D_FEAT 128
#define EPG 4

typedef float v4f __attribute__((ext_vector_type(4)));
typedef int   v4i __attribute__((ext_vector_type(4)));

// ---------------- Phase A: fp32 -> fp16 conversion (streaming) --------------
// One thread per 16 floats (64 B in, 32 B out). Threads [0,n16) -> z1,
// [n16,2*n16) -> z2. n16 = 800000 here; n16 % 256 == 0 -> block-uniform
// select, no divergence.
__global__ __launch_bounds__(256) void convert_kernel(
    const float* __restrict__ z1, const float* __restrict__ z2,
    __half* __restrict__ z1h, __half* __restrict__ z2h, int n16) {
  const int i = blockIdx.x * blockDim.x + threadIdx.x;
  if (i >= 2 * n16) return;
  const bool second = (i >= n16);
  const int j = second ? (i - n16) : i;
  const float* __restrict__ src = second ? z2 : z1;
  __half* __restrict__ dst = second ? z2h : z1h;

  const v4f* p = (const v4f*)src + 4 * (size_t)j;
  const v4f a = __builtin_nontemporal_load(p);
  const v4f b = __builtin_nontemporal_load(p + 1);
  const v4f c = __builtin_nontemporal_load(p + 2);
  const v4f e = __builtin_nontemporal_load(p + 3);

  union { __half2 h[4]; v4f f; } u0, u1;
  u0.h[0] = __floats2half2_rn(a[0], a[1]);
  u0.h[1] = __floats2half2_rn(a[2], a[3]);
  u0.h[2] = __floats2half2_rn(b[0], b[1]);
  u0.h[3] = __floats2half2_rn(b[2], b[3]);
  u1.h[0] = __floats2half2_rn(c[0], c[1]);
  u1.h[1] = __floats2half2_rn(c[2], c[3]);
  u1.h[2] = __floats2half2_rn(e[0], e[1]);
  u1.h[3] = __floats2half2_rn(e[2], e[3]);

  v4f* q = (v4f*)dst + 2 * (size_t)j;
  __builtin_nontemporal_store(u0.f, q);
  __builtin_nontemporal_store(u1.f, q + 1);
}

// ---------------- Phase B: fp16 gather + dot + sigmoid ----------------------
// 16 lanes x 16 B = 256 B = one fp16 row; 4 edges per 16-lane group.
__global__ __launch_bounds__(256) void ipd_h_kernel(
    const __half* __restrict__ z1h, const __half* __restrict__ z2h,
    const int* __restrict__ edge_index, float* __restrict__ out, int n_edges) {
  const int tid = blockIdx.x * blockDim.x + threadIdx.x;
  const int lane = tid & 15;
  const int group = tid >> 4;
  const int ebase = group * EPG;
  if (ebase >= n_edges) return;

  const v4i s4 = *(const v4i*)(edge_index + ebase);
  const v4i d4 = *(const v4i*)(edge_index + n_edges + ebase);

  // Issue all 8 row loads back-to-back (8 outstanding 16 B loads/thread).
  v4f va[EPG], vb[EPG];
#pragma unroll
  for (int i = 0; i < EPG; ++i) {
    va[i] = ((const v4f*)(z1h + (size_t)s4[i] * D_FEAT))[lane];
    vb[i] = ((const v4f*)(z2h + (size_t)d4[i] * D_FEAT))[lane];
  }

  float sum[EPG];
#pragma unroll
  for (int i = 0; i < EPG; ++i) {
    const __half2* ha = (const __half2*)&va[i];
    const __half2* hb = (const __half2*)&vb[i];
    float acc = 0.f;
#pragma unroll
    for (int k = 0; k < 4; ++k) {
      const float2 fa = __half22float2(ha[k]);
      const float2 fb = __half22float2(hb[k]);
      acc += fa.x * fb.x + fa.y * fb.y;
    }
    sum[i] = acc;
  }

#pragma unroll
  for (int off = 8; off > 0; off >>= 1) {
#pragma unroll
    for (int i = 0; i < EPG; ++i) sum[i] += __shfl_xor(sum[i], off, 16);
  }

  if (lane == 0) {
    v4f o;
    o[0] = 1.0f / (1.0f + __expf(-sum[0]));
    o[1] = 1.0f / (1.0f + __expf(-sum[1]));
    o[2] = 1.0f / (1.0f + __expf(-sum[2]));
    o[3] = 1.0f / (1.0f + __expf(-sum[3]));
    *(v4f*)(out + ebase) = o;
  }
}

// ---------------- Fallback: fp32 gather (if ws too small) -------------------
__global__ __launch_bounds__(256) void ipd_f_kernel(
    const float* __restrict__ z1, const float* __restrict__ z2,
    const int* __restrict__ edge_index, float* __restrict__ out, int n_edges) {
  const int tid = blockIdx.x * blockDim.x + threadIdx.x;
  const int lane = tid & 31;
  const int group = tid >> 5;
  const int ebase = group * EPG;
  if (ebase >= n_edges) return;

  const v4i s4 = *(const v4i*)(edge_index + ebase);
  const v4i d4 = *(const v4i*)(edge_index + n_edges + ebase);

  v4f va[EPG], vb[EPG];
#pragma unroll
  for (int i = 0; i < EPG; ++i) {
    va[i] = ((const v4f*)(z1 + (size_t)s4[i] * D_FEAT))[lane];
    vb[i] = ((const v4f*)(z2 + (size_t)d4[i] * D_FEAT))[lane];
  }

  float sum[EPG];
#pragma unroll
  for (int i = 0; i < EPG; ++i)
    sum[i] = va[i][0] * vb[i][0] + va[i][1] * vb[i][1] +
             va[i][2] * vb[i][2] + va[i][3] * vb[i][3];

#pragma unroll
  for (int off = 16; off > 0; off >>= 1) {
#pragma unroll
    for (int i = 0; i < EPG; ++i) sum[i] += __shfl_xor(sum[i], off, 32);
  }

  if (lane == 0) {
    v4f o;
    o[0] = 1.0f / (1.0f + __expf(-sum[0]));
    o[1] = 1.0f / (1.0f + __expf(-sum[1]));
    o[2] = 1.0f / (1.0f + __expf(-sum[2]));
    o[3] = 1.0f / (1.0f + __expf(-sum[3]));
    *(v4f*)(out + ebase) = o;
  }
}

extern "C" void kernel_launch(void* const* d_in, const int* in_sizes, int n_in,
                              void* d_out, int out_size, void* d_ws, size_t ws_size,
                              hipStream_t stream) {
  const float* z1 = (const float*)d_in[0];
  const float* z2 = (const float*)d_in[1];
  const int* edge_index = (const int*)d_in[2];
  float* out = (float*)d_out;

  const int n_edges = in_sizes[2] / 2;   // edge_index is [2, E]
  const int n_feat_elems = in_sizes[0];  // N_NODES * D_FEAT

  const size_t half_bytes = (size_t)n_feat_elems * sizeof(__half);
  const int block = 256;

  if (ws_size >= 2 * half_bytes && (n_feat_elems % 16) == 0) {
    __half* z1h = (__half*)d_ws;
    __half* z2h = (__half*)((char*)d_ws + half_bytes);

    const int n16 = n_feat_elems / 16;
    const int cgrid = (2 * n16 + block - 1) / block;
    convert_kernel<<<cgrid, block, 0, stream>>>(z1, z2, z1h, z2h, n16);

    const int groups = (n_edges + EPG - 1) / EPG;
    const long long total = (long long)groups * 16;
    const int grid = (int)((total + block - 1) / block);
    ipd_h_kernel<<<grid, block, 0, stream>>>(z1h, z2h, edge_index, out, n_edges);
  } else {
    const int groups = (n_edges + EPG - 1) / EPG;
    const long long total = (long long)groups * 32;
    const int grid = (int)((total + block - 1) / block);
    ipd_f_kernel<<<grid, block, 0, stream>>>(z1, z2, edge_index, out, n_edges);
  }
}

// Round 6
// 170.630 us; speedup vs baseline: 1.0789x; 1.0789x over previous
//
#include <hip/hip_runtime.h>
#include <hip/hip_bf16.h>
#include <hip/hip_fp16.h>
#include <math.h>

// InnerProductDecoder: out[e] = sigmoid(dot(z1[src[e]], z2[dst[e]])), D=128.
//
// Final structure (R5 = revert to R3, the best measured config):
//  Phase A: fp32 -> fp16 convert into d_ws (nt loads for the never-reused
//           fp32; NORMAL stores so fresh fp16 rows stay cached for Phase B
//           -- R4 showed nt stores + fewer threads regress ~13 us).
//  Phase B: 16 lanes/edge x 16 B = 256 B fp16 row gather, 4 edges per
//           16-lane group (8 outstanding loads/thread), fp32 accumulate,
//           4-step shuffle reduce, float4 store.
//
// Measured model: random-gather fetch path plateaus at ~3.3 TB/s regardless
// of request size/MLP/nt-hints (R0-R4). Gather bytes are at the fp16
// precision floor (fp8/int8/12-bit fail or graze the 2e-2 threshold).
// Convert runs ~34 us vs 24.4 us stream floor. Combined kernel time ~77 us
// vs ~69 us structural ideal.

#define D_FEAT 128
#define EPG 4

typedef float v4f __attribute__((ext_vector_type(4)));
typedef int   v4i __attribute__((ext_vector_type(4)));

// ---------------- Phase A: fp32 -> fp16 conversion (streaming) --------------
// One thread per 8 floats; threads [0,n8) handle z1, [n8,2*n8) handle z2.
// n8 % 256 == 0 for this problem, so blocks are branch-uniform.
__global__ __launch_bounds__(256) void convert_kernel(
    const float* __restrict__ z1, const float* __restrict__ z2,
    __half* __restrict__ z1h, __half* __restrict__ z2h, int n8) {
  const int i = blockIdx.x * blockDim.x + threadIdx.x;
  if (i >= 2 * n8) return;
  const bool second = (i >= n8);
  const int j = second ? (i - n8) : i;
  const float* __restrict__ src = second ? z2 : z1;
  __half* __restrict__ dst = second ? z2h : z1h;

  const v4f* p = (const v4f*)src + 2 * (size_t)j;
  const v4f a = __builtin_nontemporal_load(p);      // fp32 never reused
  const v4f b = __builtin_nontemporal_load(p + 1);
  union { __half2 h[4]; v4f f; } u;
  u.h[0] = __floats2half2_rn(a[0], a[1]);
  u.h[1] = __floats2half2_rn(a[2], a[3]);
  u.h[2] = __floats2half2_rn(b[0], b[1]);
  u.h[3] = __floats2half2_rn(b[2], b[3]);
  ((v4f*)dst)[j] = u.f;  // normal store: keep fp16 cached for the gather
}

// ---------------- Phase B: fp16 gather + dot + sigmoid ----------------------
// 16 lanes x 16 B = 256 B = one fp16 row; 4 edges per 16-lane group.
__global__ __launch_bounds__(256) void ipd_h_kernel(
    const __half* __restrict__ z1h, const __half* __restrict__ z2h,
    const int* __restrict__ edge_index, float* __restrict__ out, int n_edges) {
  const int tid = blockIdx.x * blockDim.x + threadIdx.x;
  const int lane = tid & 15;
  const int group = tid >> 4;
  const int ebase = group * EPG;
  if (ebase >= n_edges) return;

  const v4i s4 = __builtin_nontemporal_load((const v4i*)(edge_index + ebase));
  const v4i d4 = __builtin_nontemporal_load((const v4i*)(edge_index + n_edges + ebase));

  // Issue all 8 row loads back-to-back (8 outstanding 16 B loads/thread).
  v4f va[EPG], vb[EPG];
#pragma unroll
  for (int i = 0; i < EPG; ++i) {
    va[i] = ((const v4f*)(z1h + (size_t)s4[i] * D_FEAT))[lane];
    vb[i] = ((const v4f*)(z2h + (size_t)d4[i] * D_FEAT))[lane];
  }

  float sum[EPG];
#pragma unroll
  for (int i = 0; i < EPG; ++i) {
    const __half2* ha = (const __half2*)&va[i];
    const __half2* hb = (const __half2*)&vb[i];
    float acc = 0.f;
#pragma unroll
    for (int k = 0; k < 4; ++k) {
      const float2 fa = __half22float2(ha[k]);
      const float2 fb = __half22float2(hb[k]);
      acc += fa.x * fb.x + fa.y * fb.y;
    }
    sum[i] = acc;
  }

#pragma unroll
  for (int off = 8; off > 0; off >>= 1) {
#pragma unroll
    for (int i = 0; i < EPG; ++i) sum[i] += __shfl_xor(sum[i], off, 16);
  }

  if (lane == 0) {
    v4f o;
    o[0] = 1.0f / (1.0f + __expf(-sum[0]));
    o[1] = 1.0f / (1.0f + __expf(-sum[1]));
    o[2] = 1.0f / (1.0f + __expf(-sum[2]));
    o[3] = 1.0f / (1.0f + __expf(-sum[3]));
    __builtin_nontemporal_store(o, (v4f*)(out + ebase));  // written once
  }
}

// ---------------- Fallback: fp32 gather (if ws too small) -------------------
__global__ __launch_bounds__(256) void ipd_f_kernel(
    const float* __restrict__ z1, const float* __restrict__ z2,
    const int* __restrict__ edge_index, float* __restrict__ out, int n_edges) {
  const int tid = blockIdx.x * blockDim.x + threadIdx.x;
  const int lane = tid & 31;
  const int group = tid >> 5;
  const int ebase = group * EPG;
  if (ebase >= n_edges) return;

  const v4i s4 = *(const v4i*)(edge_index + ebase);
  const v4i d4 = *(const v4i*)(edge_index + n_edges + ebase);

  v4f va[EPG], vb[EPG];
#pragma unroll
  for (int i = 0; i < EPG; ++i) {
    va[i] = ((const v4f*)(z1 + (size_t)s4[i] * D_FEAT))[lane];
    vb[i] = ((const v4f*)(z2 + (size_t)d4[i] * D_FEAT))[lane];
  }

  float sum[EPG];
#pragma unroll
  for (int i = 0; i < EPG; ++i)
    sum[i] = va[i][0] * vb[i][0] + va[i][1] * vb[i][1] +
             va[i][2] * vb[i][2] + va[i][3] * vb[i][3];

#pragma unroll
  for (int off = 16; off > 0; off >>= 1) {
#pragma unroll
    for (int i = 0; i < EPG; ++i) sum[i] += __shfl_xor(sum[i], off, 32);
  }

  if (lane == 0) {
    v4f o;
    o[0] = 1.0f / (1.0f + __expf(-sum[0]));
    o[1] = 1.0f / (1.0f + __expf(-sum[1]));
    o[2] = 1.0f / (1.0f + __expf(-sum[2]));
    o[3] = 1.0f / (1.0f + __expf(-sum[3]));
    *(v4f*)(out + ebase) = o;
  }
}

extern "C" void kernel_launch(void* const* d_in, const int* in_sizes, int n_in,
                              void* d_out, int out_size, void* d_ws, size_t ws_size,
                              hipStream_t stream) {
  const float* z1 = (const float*)d_in[0];
  const float* z2 = (const float*)d_in[1];
  const int* edge_index = (const int*)d_in[2];
  float* out = (float*)d_out;

  const int n_edges = in_sizes[2] / 2;   // edge_index is [2, E]
  const int n_feat_elems = in_sizes[0];  // N_NODES * D_FEAT

  const size_t half_bytes = (size_t)n_feat_elems * sizeof(__half);
  const int block = 256;

  if (ws_size >= 2 * half_bytes && (n_feat_elems % 8) == 0) {
    __half* z1h = (__half*)d_ws;
    __half* z2h = (__half*)((char*)d_ws + half_bytes);

    const int n8 = n_feat_elems / 8;
    const int cgrid = (2 * n8 + block - 1) / block;
    convert_kernel<<<cgrid, block, 0, stream>>>(z1, z2, z1h, z2h, n8);

    const int groups = (n_edges + EPG - 1) / EPG;
    const long long total = (long long)groups * 16;
    const int grid = (int)((total + block - 1) / block);
    ipd_h_kernel<<<grid, block, 0, stream>>>(z1h, z2h, edge_index, out, n_edges);
  } else {
    const int groups = (n_edges + EPG - 1) / EPG;
    const long long total = (long long)groups * 32;
    const int grid = (int)((total + block - 1) / block);
    ipd_f_kernel<<<grid, block, 0, stream>>>(z1, z2, edge_index, out, n_edges);
  }
}